// Round 4
// baseline (11457.178 us; speedup 1.0000x reference)
//
#include <hip/hip_runtime.h>
#include <hip/hip_bf16.h>
#include <math.h>

// Problem constants (B=512, T=128, D=64, H=512, C=10)
#define B 512
#define T 128
#define D 64
#define H 512
#define NC 10
#define FOURH 2048
#define PRED_ROW 8128        // (T-1)*D
#define PRED_ELEMS 4161536   // B*(T-1)*D
#define MISSING_V 128.0f
#define KC0 18               // (D+H)/32
#define KC1 32               // (H+H)/32
#define BH (B * H)
#define NBLK 256

typedef __attribute__((ext_vector_type(8))) short bf16x8;
typedef __attribute__((ext_vector_type(4))) float f32x4;

__device__ __forceinline__ float sigm(float x) {
    return 1.0f / (1.0f + __expf(-x));
}
__device__ __forceinline__ ushort f2bf(float x) {
    __hip_bfloat16 h = __float2bfloat16(x);   // RNE
    return *(ushort*)&h;
}
__device__ __forceinline__ float bf2f(ushort u) {
    __hip_bfloat16 h;
    *(ushort*)&h = u;
    return __bfloat162float(h);
}

// ---------------------------------------------------------------------------
// Weight pack: B-fragment layout (validated R3), hi/lo split.
// idx(k,n; KCt) = (((n>>4)*KCt + (k>>5))*4 + ((k>>3)&3))*128 + (n&15)*8 + (k&7)
// Wp: same with KCt=16 over W[512][64].
// ---------------------------------------------------------------------------
__global__ __launch_bounds__(256) void pack_weights(
    const float* __restrict__ k0, const float* __restrict__ r0,
    const float* __restrict__ k1, const float* __restrict__ r1,
    const float* __restrict__ W,
    ushort* __restrict__ Bh0, ushort* __restrict__ Bl0,
    ushort* __restrict__ Bh1, ushort* __restrict__ Bl1,
    ushort* __restrict__ Wph, ushort* __restrict__ Wpl) {
    const int n0 = 576 * 2048;
    const int n1 = 1024 * 2048;
    const int nw = 512 * 64;
    const int total = n0 + n1 + nw;
    for (int idx = blockIdx.x * blockDim.x + threadIdx.x; idx < total;
         idx += gridDim.x * blockDim.x) {
        float v;
        ushort *dh, *dl;
        size_t didx;
        if (idx < n0) {
            int k = idx >> 11, n = idx & 2047;
            v = (k < D) ? k0[k * 2048 + n] : r0[(k - D) * 2048 + n];
            didx = (((size_t)(n >> 4) * KC0 + (k >> 5)) * 4 + ((k >> 3) & 3)) * 128
                   + (n & 15) * 8 + (k & 7);
            dh = Bh0; dl = Bl0;
        } else if (idx < n0 + n1) {
            int j = idx - n0;
            int k = j >> 11, n = j & 2047;
            v = (k < H) ? k1[k * 2048 + n] : r1[(k - H) * 2048 + n];
            didx = (((size_t)(n >> 4) * KC1 + (k >> 5)) * 4 + ((k >> 3) & 3)) * 128
                   + (n & 15) * 8 + (k & 7);
            dh = Bh1; dl = Bl1;
        } else {
            int j = idx - n0 - n1;
            int k = j >> 6, c = j & 63;
            v = W[k * 64 + c];
            didx = (((size_t)(c >> 4) * 16 + (k >> 5)) * 4 + ((k >> 3) & 3)) * 128
                   + (c & 15) * 8 + (k & 7);
            dh = Wph; dl = Wpl;
        }
        ushort hb_ = f2bf(v);
        dh[didx] = hb_;
        dl[didx] = f2bf(v - bf2f(hb_));
    }
}

// ---------------------------------------------------------------------------
// Zero region: initial h-packs (4 x 512KB) + barrier cnt/sense + lp scalar.
// ---------------------------------------------------------------------------
__global__ __launch_bounds__(256) void init_zero(float4* __restrict__ z, int n4) {
    for (int i = blockIdx.x * blockDim.x + threadIdx.x; i < n4;
         i += gridDim.x * blockDim.x)
        z[i] = make_float4(0.f, 0.f, 0.f, 0.f);
}

// ---------------------------------------------------------------------------
// Device-scope grid barrier (sense-reversing, all 256 blocks co-resident).
// ---------------------------------------------------------------------------
__device__ __forceinline__ void gbar(int* cnt, int* sense, int ep) {
    __syncthreads();
    if (threadIdx.x == 0) {
        __threadfence();  // release this block's global writes to agent scope
        int old = __hip_atomic_fetch_add(cnt, 1, __ATOMIC_ACQ_REL,
                                         __HIP_MEMORY_SCOPE_AGENT);
        if (old == NBLK - 1) {
            __hip_atomic_store(cnt, 0, __ATOMIC_RELAXED, __HIP_MEMORY_SCOPE_AGENT);
            __hip_atomic_store(sense, ep, __ATOMIC_RELEASE, __HIP_MEMORY_SCOPE_AGENT);
        } else {
            while (__hip_atomic_load(sense, __ATOMIC_RELAXED,
                                     __HIP_MEMORY_SCOPE_AGENT) < ep)
                __builtin_amdgcn_s_sleep(8);
        }
        __threadfence();  // acquire side
    }
    __syncthreads();
}

// 12 MFMAs of one 32-k chunk, 3-pass hi/lo (hh, hl, lh), 4 column-tiles.
#define MFMA_CHUNK(AHI, ALO)                                                   \
    {                                                                          \
        bf16x8 b0h = *(const bf16x8*)ph0, b0l = *(const bf16x8*)pl0;           \
        bf16x8 b1h = *(const bf16x8*)ph1, b1l = *(const bf16x8*)pl1;           \
        bf16x8 b2h = *(const bf16x8*)ph2, b2l = *(const bf16x8*)pl2;           \
        bf16x8 b3h = *(const bf16x8*)ph3, b3l = *(const bf16x8*)pl3;           \
        acc0 = __builtin_amdgcn_mfma_f32_16x16x32_bf16(AHI, b0h, acc0, 0, 0, 0); \
        acc1 = __builtin_amdgcn_mfma_f32_16x16x32_bf16(AHI, b1h, acc1, 0, 0, 0); \
        acc2 = __builtin_amdgcn_mfma_f32_16x16x32_bf16(AHI, b2h, acc2, 0, 0, 0); \
        acc3 = __builtin_amdgcn_mfma_f32_16x16x32_bf16(AHI, b3h, acc3, 0, 0, 0); \
        acc0 = __builtin_amdgcn_mfma_f32_16x16x32_bf16(AHI, b0l, acc0, 0, 0, 0); \
        acc1 = __builtin_amdgcn_mfma_f32_16x16x32_bf16(AHI, b1l, acc1, 0, 0, 0); \
        acc2 = __builtin_amdgcn_mfma_f32_16x16x32_bf16(AHI, b2l, acc2, 0, 0, 0); \
        acc3 = __builtin_amdgcn_mfma_f32_16x16x32_bf16(AHI, b3l, acc3, 0, 0, 0); \
        acc0 = __builtin_amdgcn_mfma_f32_16x16x32_bf16(ALO, b0h, acc0, 0, 0, 0); \
        acc1 = __builtin_amdgcn_mfma_f32_16x16x32_bf16(ALO, b1h, acc1, 0, 0, 0); \
        acc2 = __builtin_amdgcn_mfma_f32_16x16x32_bf16(ALO, b2h, acc2, 0, 0, 0); \
        acc3 = __builtin_amdgcn_mfma_f32_16x16x32_bf16(ALO, b3h, acc3, 0, 0, 0); \
        ph0 += 512; pl0 += 512; ph1 += 512; pl1 += 512;                        \
        ph2 += 512; pl2 += 512; ph3 += 512; pl3 += 512;                        \
    }

// ---------------------------------------------------------------------------
// Persistent kernel: entire T-loop. 256 blocks (8 rowblocks x 32 hblocks,
// XCD-grouped by hblock) x 512 threads (4 wrow x 2 K-half waves).
// Per step: phase A = pred(MFMA,fused)+impute(->LDS A-frags)+L0 GEMM+cell;
// grid barrier; phase B = L1 GEMM+cell; grid barrier. c0/c1 in registers.
// ---------------------------------------------------------------------------
__global__ __launch_bounds__(512) void lstm_persistent(
    const float* __restrict__ inputs, const float* __restrict__ bvec,
    const float* __restrict__ b0, const float* __restrict__ b1,
    const ushort* __restrict__ Wr0h, const ushort* __restrict__ Wr0l,
    const ushort* __restrict__ Wr1h, const ushort* __restrict__ Wr1l,
    const ushort* __restrict__ Wph, const ushort* __restrict__ Wpl,
    ushort* __restrict__ h0Ah, ushort* __restrict__ h0Al,
    ushort* __restrict__ h1Ah, ushort* __restrict__ h1Al,
    ushort* __restrict__ h0Bh, ushort* __restrict__ h0Bl,
    ushort* __restrict__ h1Bh, ushort* __restrict__ h1Bl,
    float* __restrict__ h1f32, float* __restrict__ predout,
    int* __restrict__ cnt, int* __restrict__ sense) {
    __shared__ float red[4][4][64][4];       // 16 KB K-split reduce
    __shared__ ushort curAh[8][66][8];       // cur A-frags hi (row-padded)
    __shared__ ushort curAl[8][66][8];       // cur A-frags lo

    const int bid = blockIdx.x;
    const int xcd = bid & 7;
    const int wi = bid >> 3;
    const int rb = wi >> 2;                  // 0..7  rowblock (64 rows)
    const int hb = xcd * 4 + (wi & 3);       // 0..31 hblock (16 h-units)
    const int tid = threadIdx.x;
    const int wid = tid >> 6;
    const int l = tid & 63;
    const int wrow = wid & 3;                // row-subtile (16 rows)
    const int ks = wid >> 2;                 // K-half
    const int c16 = l & 15;
    const int sub = l >> 4;
    const int lr16 = wrow * 16 + c16;        // A-frag local row
    const int arow = rb * 64 + lr16;         // A-frag global row
    const int hc = hb * 16 + c16;            // h-unit owned in epilogue

    // persistent cell states + biases (used by ks==0 threads)
    float c0r[4] = {0.f, 0.f, 0.f, 0.f};
    float c1r[4] = {0.f, 0.f, 0.f, 0.f};
    const float bI0 = b0[hc], bF0 = b0[H + hc], bG0 = b0[2 * H + hc], bO0 = b0[3 * H + hc];
    const float bI1 = b1[hc], bF1 = b1[H + hc], bG1 = b1[2 * H + hc], bO1 = b1[3 * H + hc];
    float bvr[4];
#pragma unroll
    for (int ct = 0; ct < 4; ++ct) bvr[ct] = bvec[ct * 16 + c16];

    // ping-pong pack pointers
    const ushort* h0rh = h0Ah; const ushort* h0rl = h0Al;
    const ushort* h1rh = h1Ah; const ushort* h1rl = h1Al;
    ushort* h0wh = h0Bh; ushort* h0wl = h0Bl;
    ushort* h1wh = h1Bh; ushort* h1wl = h1Bl;

    const size_t fragoff = (size_t)sub * 128 + c16 * 8;   // within-chunk B offset
    const size_t arow8 = (size_t)arow * 8;

    for (int t = 0; t < T; ++t) {
        // =================== phase A ===================
        if (t > 0) {
            // ---- pred = h1(t-1) @ W + bvec (64 rows x 64 cols, K=512) ----
            f32x4 acc0 = {0.f, 0.f, 0.f, 0.f}, acc1 = acc0, acc2 = acc0, acc3 = acc0;
            const int kcS = ks * 8;
            const ushort* ph0 = Wph + (size_t)(0 * 16 + kcS) * 512 + fragoff;
            const ushort* pl0 = Wpl + (size_t)(0 * 16 + kcS) * 512 + fragoff;
            const ushort* ph1 = Wph + (size_t)(1 * 16 + kcS) * 512 + fragoff;
            const ushort* pl1 = Wpl + (size_t)(1 * 16 + kcS) * 512 + fragoff;
            const ushort* ph2 = Wph + (size_t)(2 * 16 + kcS) * 512 + fragoff;
            const ushort* pl2 = Wpl + (size_t)(2 * 16 + kcS) * 512 + fragoff;
            const ushort* ph3 = Wph + (size_t)(3 * 16 + kcS) * 512 + fragoff;
            const ushort* pl3 = Wpl + (size_t)(3 * 16 + kcS) * 512 + fragoff;
            const ushort* pah = h1rh + ((size_t)kcS * 4 + sub) * 4096 + arow8;
            const ushort* pal = h1rl + ((size_t)kcS * 4 + sub) * 4096 + arow8;
#pragma unroll 2
            for (int kc = 0; kc < 8; ++kc) {
                bf16x8 ahi = *(const bf16x8*)pah;
                bf16x8 alo = *(const bf16x8*)pal;
                MFMA_CHUNK(ahi, alo);
                pah += 16384; pal += 16384;
            }
            if (ks == 1) {
                *(f32x4*)&red[wrow][0][l][0] = acc0;
                *(f32x4*)&red[wrow][1][l][0] = acc1;
                *(f32x4*)&red[wrow][2][l][0] = acc2;
                *(f32x4*)&red[wrow][3][l][0] = acc3;
            }
            __syncthreads();
            if (ks == 0) {
#define PRED_EPI(CT, ACC)                                                      \
                {                                                              \
                    f32x4 a = ACC;                                             \
                    a += *(f32x4*)&red[wrow][CT][l][0];                        \
                    const int col = CT * 16 + c16;                             \
                    _Pragma("unroll")                                          \
                    for (int reg = 0; reg < 4; ++reg) {                        \
                        int lr = wrow * 16 + sub * 4 + reg;                    \
                        int grow = rb * 64 + lr;                               \
                        float pv = a[reg] + bvr[CT];                           \
                        predout[(size_t)grow * PRED_ROW + (size_t)(t - 1) * D + col] = pv; \
                        float xv = inputs[(size_t)grow * 8192 + (size_t)t * D + col]; \
                        float cv = (xv == MISSING_V) ? pv : xv;                \
                        ushort hbv = f2bf(cv);                                 \
                        curAh[col >> 3][lr][col & 7] = hbv;                    \
                        curAl[col >> 3][lr][col & 7] = f2bf(cv - bf2f(hbv));   \
                    }                                                          \
                }
                PRED_EPI(0, acc0) PRED_EPI(1, acc1) PRED_EPI(2, acc2) PRED_EPI(3, acc3)
#undef PRED_EPI
            }
        } else {
            // t == 0: cur = raw x[:,0,:]
            if (ks == 0) {
#pragma unroll
                for (int ct = 0; ct < 4; ++ct) {
                    const int col = ct * 16 + c16;
#pragma unroll
                    for (int reg = 0; reg < 4; ++reg) {
                        int lr = wrow * 16 + sub * 4 + reg;
                        int grow = rb * 64 + lr;
                        float cv = inputs[(size_t)grow * 8192 + col];
                        ushort hbv = f2bf(cv);
                        curAh[col >> 3][lr][col & 7] = hbv;
                        curAl[col >> 3][lr][col & 7] = f2bf(cv - bf2f(hbv));
                    }
                }
            }
        }
        __syncthreads();   // curA ready (and red free)

        // ---- L0 GEMM: z0 = [cur | h0(t-1)] @ Wr0, fused cell -> h0(t) ----
        {
            f32x4 acc0 = {0.f, 0.f, 0.f, 0.f}, acc1 = acc0, acc2 = acc0, acc3 = acc0;
            const int kcS = ks * 9;
            const ushort* ph0 = Wr0h + ((size_t)(0 * 32 + hb) * KC0 + kcS) * 512 + fragoff;
            const ushort* pl0 = Wr0l + ((size_t)(0 * 32 + hb) * KC0 + kcS) * 512 + fragoff;
            const ushort* ph1 = Wr0h + ((size_t)(1 * 32 + hb) * KC0 + kcS) * 512 + fragoff;
            const ushort* pl1 = Wr0l + ((size_t)(1 * 32 + hb) * KC0 + kcS) * 512 + fragoff;
            const ushort* ph2 = Wr0h + ((size_t)(2 * 32 + hb) * KC0 + kcS) * 512 + fragoff;
            const ushort* pl2 = Wr0l + ((size_t)(2 * 32 + hb) * KC0 + kcS) * 512 + fragoff;
            const ushort* ph3 = Wr0h + ((size_t)(3 * 32 + hb) * KC0 + kcS) * 512 + fragoff;
            const ushort* pl3 = Wr0l + ((size_t)(3 * 32 + hb) * KC0 + kcS) * 512 + fragoff;
            if (ks == 0) {
#pragma unroll
                for (int kc = 0; kc < 2; ++kc) {
                    bf16x8 ahi = *(const bf16x8*)&curAh[kc * 4 + sub][lr16][0];
                    bf16x8 alo = *(const bf16x8*)&curAl[kc * 4 + sub][lr16][0];
                    MFMA_CHUNK(ahi, alo);
                }
                const ushort* pah = h0rh + (size_t)sub * 4096 + arow8;   // kc=2 -> kgrp 0
                const ushort* pal = h0rl + (size_t)sub * 4096 + arow8;
#pragma unroll 2
                for (int kc = 2; kc < 9; ++kc) {
                    bf16x8 ahi = *(const bf16x8*)pah;
                    bf16x8 alo = *(const bf16x8*)pal;
                    MFMA_CHUNK(ahi, alo);
                    pah += 16384; pal += 16384;
                }
            } else {
                const ushort* pah = h0rh + ((size_t)7 * 4 + sub) * 4096 + arow8;  // kc=9 -> kgrp 28
                const ushort* pal = h0rl + ((size_t)7 * 4 + sub) * 4096 + arow8;
#pragma unroll 2
                for (int kc = 9; kc < 18; ++kc) {
                    bf16x8 ahi = *(const bf16x8*)pah;
                    bf16x8 alo = *(const bf16x8*)pal;
                    MFMA_CHUNK(ahi, alo);
                    pah += 16384; pal += 16384;
                }
            }
            if (ks == 1) {
                *(f32x4*)&red[wrow][0][l][0] = acc0;
                *(f32x4*)&red[wrow][1][l][0] = acc1;
                *(f32x4*)&red[wrow][2][l][0] = acc2;
                *(f32x4*)&red[wrow][3][l][0] = acc3;
            }
            __syncthreads();
            if (ks == 0) {
                acc0 += *(f32x4*)&red[wrow][0][l][0];
                acc1 += *(f32x4*)&red[wrow][1][l][0];
                acc2 += *(f32x4*)&red[wrow][2][l][0];
                acc3 += *(f32x4*)&red[wrow][3][l][0];
#pragma unroll
                for (int reg = 0; reg < 4; ++reg) {
                    int grow = rb * 64 + wrow * 16 + sub * 4 + reg;
                    float zi = acc0[reg] + bI0, zf = acc1[reg] + bF0;
                    float zg = acc2[reg] + bG0, zo = acc3[reg] + bO0;
                    float cn = sigm(zf) * c0r[reg] + sigm(zi) * tanhf(zg);
                    c0r[reg] = cn;
                    float hn = sigm(zo) * tanhf(cn);
                    size_t po = ((size_t)(hc >> 3) * 512 + grow) * 8 + (hc & 7);
                    ushort hh = f2bf(hn);
                    h0wh[po] = hh;
                    h0wl[po] = f2bf(hn - bf2f(hh));
                }
            }
        }
        gbar(cnt, sense, 2 * t + 1);

        // =================== phase B: L1 ===================
        {
            f32x4 acc0 = {0.f, 0.f, 0.f, 0.f}, acc1 = acc0, acc2 = acc0, acc3 = acc0;
            const int kcS = ks * 16;
            const ushort* ph0 = Wr1h + ((size_t)(0 * 32 + hb) * KC1 + kcS) * 512 + fragoff;
            const ushort* pl0 = Wr1l + ((size_t)(0 * 32 + hb) * KC1 + kcS) * 512 + fragoff;
            const ushort* ph1 = Wr1h + ((size_t)(1 * 32 + hb) * KC1 + kcS) * 512 + fragoff;
            const ushort* pl1 = Wr1l + ((size_t)(1 * 32 + hb) * KC1 + kcS) * 512 + fragoff;
            const ushort* ph2 = Wr1h + ((size_t)(2 * 32 + hb) * KC1 + kcS) * 512 + fragoff;
            const ushort* pl2 = Wr1l + ((size_t)(2 * 32 + hb) * KC1 + kcS) * 512 + fragoff;
            const ushort* ph3 = Wr1h + ((size_t)(3 * 32 + hb) * KC1 + kcS) * 512 + fragoff;
            const ushort* pl3 = Wr1l + ((size_t)(3 * 32 + hb) * KC1 + kcS) * 512 + fragoff;
            // ks0: A1 = h0(t) (just produced); ks1: A2 = h1(t-1)
            const ushort* pah = (ks == 0 ? (const ushort*)h0wh : h1rh) + (size_t)sub * 4096 + arow8;
            const ushort* pal = (ks == 0 ? (const ushort*)h0wl : h1rl) + (size_t)sub * 4096 + arow8;
#pragma unroll 2
            for (int kc = 0; kc < 16; ++kc) {
                bf16x8 ahi = *(const bf16x8*)pah;
                bf16x8 alo = *(const bf16x8*)pal;
                MFMA_CHUNK(ahi, alo);
                pah += 16384; pal += 16384;
            }
            if (ks == 1) {
                *(f32x4*)&red[wrow][0][l][0] = acc0;
                *(f32x4*)&red[wrow][1][l][0] = acc1;
                *(f32x4*)&red[wrow][2][l][0] = acc2;
                *(f32x4*)&red[wrow][3][l][0] = acc3;
            }
            __syncthreads();
            if (ks == 0) {
                acc0 += *(f32x4*)&red[wrow][0][l][0];
                acc1 += *(f32x4*)&red[wrow][1][l][0];
                acc2 += *(f32x4*)&red[wrow][2][l][0];
                acc3 += *(f32x4*)&red[wrow][3][l][0];
#pragma unroll
                for (int reg = 0; reg < 4; ++reg) {
                    int grow = rb * 64 + wrow * 16 + sub * 4 + reg;
                    float zi = acc0[reg] + bI1, zf = acc1[reg] + bF1;
                    float zg = acc2[reg] + bG1, zo = acc3[reg] + bO1;
                    float cn = sigm(zf) * c1r[reg] + sigm(zi) * tanhf(zg);
                    c1r[reg] = cn;
                    float hn = sigm(zo) * tanhf(cn);
                    size_t po = ((size_t)(hc >> 3) * 512 + grow) * 8 + (hc & 7);
                    ushort hh = f2bf(hn);
                    h1wh[po] = hh;
                    h1wl[po] = f2bf(hn - bf2f(hh));
                    if (t == T - 1) h1f32[(size_t)grow * H + hc] = hn;
                }
            }
        }
        gbar(cnt, sense, 2 * t + 2);

        // swap ping-pong packs
        { const ushort* s;
          s = h0rh; h0rh = h0wh; h0wh = (ushort*)s;
          s = h0rl; h0rl = h0wl; h0wl = (ushort*)s;
          s = h1rh; h1rh = h1wh; h1wh = (ushort*)s;
          s = h1rl; h1rl = h1wl; h1wl = (ushort*)s; }
    }
}

// ---------------------------------------------------------------------------
// Fused: M output copy + masked-squared-error reduction into *accum.
// ---------------------------------------------------------------------------
__global__ __launch_bounds__(256) void pred_loss_reduce(
    const float* __restrict__ pred, const float* __restrict__ targ,
    const float* __restrict__ mask, float* __restrict__ Mout,
    float* __restrict__ accum) {
    const int n4 = PRED_ELEMS / 4;
    float part = 0.f;
    for (int i = blockIdx.x * blockDim.x + threadIdx.x; i < n4;
         i += gridDim.x * blockDim.x) {
        float4 p = ((const float4*)pred)[i];
        float4 t = ((const float4*)targ)[i];
        float4 m = ((const float4*)mask)[i];
        ((float4*)Mout)[i] = m;
        float dx = (t.x - p.x) * m.x;
        float dy = (t.y - p.y) * m.y;
        float dz = (t.z - p.z) * m.z;
        float dw = (t.w - p.w) * m.w;
        part += dx * dx + dy * dy + dz * dz + dw * dw;
    }
#pragma unroll
    for (int off = 32; off > 0; off >>= 1) part += __shfl_down(part, off, 64);
    __shared__ float wsum[4];
    int lane = threadIdx.x & 63, wid = threadIdx.x >> 6;
    if (lane == 0) wsum[wid] = part;
    __syncthreads();
    if (threadIdx.x == 0)
        atomicAdd(accum, wsum[0] + wsum[1] + wsum[2] + wsum[3]);
}

// ---------------------------------------------------------------------------
// Final: logits = h1_last @ Wc + bc; log-softmax loss; accuracy.
// ---------------------------------------------------------------------------
__global__ __launch_bounds__(64) void final_loss(
    const float* __restrict__ h1, const float* __restrict__ Wc,
    const float* __restrict__ bc, const float* __restrict__ label,
    const float* __restrict__ lp_accum, float* __restrict__ loss,
    float* __restrict__ acc_out) {
    const int b = blockIdx.x;
    const int lane = threadIdx.x;
    float partial[NC];
#pragma unroll
    for (int c = 0; c < NC; ++c) partial[c] = 0.f;
    for (int k = lane; k < H; k += 64) {
        float hv = h1[(size_t)b * H + k];
#pragma unroll
        for (int c = 0; c < NC; ++c) partial[c] += hv * Wc[k * NC + c];
    }
    float logits[NC];
#pragma unroll
    for (int c = 0; c < NC; ++c) {
        float v = partial[c];
#pragma unroll
        for (int off = 32; off > 0; off >>= 1) v += __shfl_down(v, off, 64);
        logits[c] = v + bc[c];
    }
    if (lane == 0) {
        float mx = logits[0];
#pragma unroll
        for (int c = 1; c < NC; ++c) mx = fmaxf(mx, logits[c]);
        float se = 0.f;
#pragma unroll
        for (int c = 0; c < NC; ++c) se += expf(logits[c] - mx);
        float lse = logf(se);
        float lcls = 0.f;
        int am_p = 0, am_l = 0;
        float bp = logits[0], bl = label[(size_t)b * NC];
#pragma unroll
        for (int c = 0; c < NC; ++c) {
            float lt = label[(size_t)b * NC + c];
            lcls -= lt * (logits[c] - mx - lse);
            if (c > 0) {
                if (logits[c] > bp) { bp = logits[c]; am_p = c; }
                if (lt > bl) { bl = lt; am_l = c; }
            }
        }
        float lp = lp_accum[0] * (1.0f / (float)PRED_ELEMS) * (1.0f / (float)B);
        loss[b] = lcls + lp;
        acc_out[b] = (am_p == am_l) ? 1.f : 0.f;
    }
}

// ---------------------------------------------------------------------------
extern "C" void kernel_launch(void* const* d_in, const int* in_sizes, int n_in,
                              void* d_out, int out_size, void* d_ws,
                              size_t ws_size, hipStream_t stream) {
    const float* inputs  = (const float*)d_in[0];
    const float* ptarget = (const float*)d_in[1];
    const float* mask    = (const float*)d_in[2];
    const float* label   = (const float*)d_in[3];
    const float* W       = (const float*)d_in[4];
    const float* bvec    = (const float*)d_in[5];
    const float* k0      = (const float*)d_in[6];
    const float* r0      = (const float*)d_in[7];
    const float* b0      = (const float*)d_in[8];
    const float* k1      = (const float*)d_in[9];
    const float* r1      = (const float*)d_in[10];
    const float* b1      = (const float*)d_in[11];
    const float* Wc      = (const float*)d_in[12];
    const float* bc      = (const float*)d_in[13];

    float* out = (float*)d_out;
    float* loss    = out;
    float* predout = out + B;
    float* Mout    = out + B + PRED_ELEMS;
    float* accout  = out + B + 2 * (size_t)PRED_ELEMS;

    // ---- ws layout ----
    char* w = (char*)d_ws;
    ushort* h0Ah = (ushort*)w; w += (size_t)BH * 2;   // zeroed region start
    ushort* h0Al = (ushort*)w; w += (size_t)BH * 2;
    ushort* h1Ah = (ushort*)w; w += (size_t)BH * 2;
    ushort* h1Al = (ushort*)w; w += (size_t)BH * 2;
    int*    cnt   = (int*)w;
    int*    sense = (int*)(w + 4);
    float*  lp    = (float*)(w + 8);
    w += 64;
    const int zero_n4 = (int)((4 * (size_t)BH * 2 + 64) / 16);
    ushort* h0Bh = (ushort*)w; w += (size_t)BH * 2;
    ushort* h0Bl = (ushort*)w; w += (size_t)BH * 2;
    ushort* h1Bh = (ushort*)w; w += (size_t)BH * 2;
    ushort* h1Bl = (ushort*)w; w += (size_t)BH * 2;
    float*  h1f32 = (float*)w; w += (size_t)BH * 4;
    ushort* Wr0h = (ushort*)w; w += (size_t)576 * 2048 * 2;
    ushort* Wr0l = (ushort*)w; w += (size_t)576 * 2048 * 2;
    ushort* Wr1h = (ushort*)w; w += (size_t)1024 * 2048 * 2;
    ushort* Wr1l = (ushort*)w; w += (size_t)1024 * 2048 * 2;
    ushort* Wph  = (ushort*)w; w += (size_t)512 * 64 * 2;
    ushort* Wpl  = (ushort*)w; w += (size_t)512 * 64 * 2;

    pack_weights<<<2048, 256, 0, stream>>>(k0, r0, k1, r1, W,
                                           Wr0h, Wr0l, Wr1h, Wr1l, Wph, Wpl);
    init_zero<<<512, 256, 0, stream>>>((float4*)d_ws, zero_n4);

    lstm_persistent<<<NBLK, 512, 0, stream>>>(
        inputs, bvec, b0, b1, Wr0h, Wr0l, Wr1h, Wr1l, Wph, Wpl,
        h0Ah, h0Al, h1Ah, h1Al, h0Bh, h0Bl, h1Bh, h1Bl,
        h1f32, predout, cnt, sense);

    pred_loss_reduce<<<1024, 256, 0, stream>>>(predout, ptarget, mask, Mout, lp);
    final_loss<<<B, 64, 0, stream>>>(h1f32, Wc, bc, label, lp, loss, accout);
}

// Round 6
// 10721.864 us; speedup vs baseline: 1.0686x; 1.0686x over previous
//
#include <hip/hip_runtime.h>
#include <hip/hip_bf16.h>
#include <math.h>

// Problem constants (B=512, T=128, D=64, H=512, C=10)
#define B 512
#define T 128
#define D 64
#define H 512
#define NC 10
#define FOURH 2048
#define PRED_ROW 8128        // (T-1)*D
#define PRED_ELEMS 4161536   // B*(T-1)*D
#define MISSING_V 128.0f
#define KC0 18               // (D+H)/32
#define KC1 32               // (H+H)/32
#define BH (B * H)
#define NBLK 256

typedef __attribute__((ext_vector_type(8))) short bf16x8;
typedef __attribute__((ext_vector_type(4))) float f32x4;

__device__ __forceinline__ float sigm(float x) {
    return 1.0f / (1.0f + __expf(-x));
}
__device__ __forceinline__ ushort f2bf(float x) {
    __hip_bfloat16 h = __float2bfloat16(x);   // RNE
    return *(ushort*)&h;
}
__device__ __forceinline__ float bf2f(ushort u) {
    __hip_bfloat16 h;
    *(ushort*)&h = u;
    return __bfloat162float(h);
}

// Coherent (XCD-L2-bypassing) accesses for cross-block h-state. sc0 sc1 makes
// the single access agent-coherent WITHOUT any cache-invalidating fence, so
// the weights stay resident in each XCD's L2 across the whole T-loop.
__device__ __forceinline__ void sc_ld16(const ushort* p, uint4& d) {
    asm volatile("global_load_dwordx4 %0, %1, off sc0 sc1"
                 : "=v"(d) : "v"(p) : "memory");
}
__device__ __forceinline__ void sc_st16b(ushort* p, ushort v) {
    uint q = (uint)v;
    asm volatile("global_store_short %0, %1, off sc0 sc1"
                 :: "v"(p), "v"(q) : "memory");
}
#define WAITV                                                  \
    {                                                          \
        asm volatile("s_waitcnt vmcnt(0)" ::: "memory");       \
        __builtin_amdgcn_sched_barrier(0);                     \
    }

__device__ __forceinline__ bf16x8 u2b(uint4 v) {
    union { uint4 u; bf16x8 b; } c;
    c.u = v;
    return c.b;
}

// Load B-fragments for one 32-k chunk: 4 col-tiles, hi+lo (cached loads).
#define LOADB(BH_, BL_)                                        \
    bf16x8 BH_[4], BL_[4];                                     \
    _Pragma("unroll")                                          \
    for (int q_ = 0; q_ < 4; ++q_) {                           \
        BH_[q_] = *(const bf16x8*)ph[q_];                      \
        BL_[q_] = *(const bf16x8*)pl[q_];                      \
        ph[q_] += 512; pl[q_] += 512;                          \
    }

// 12 MFMAs of one chunk: 3-pass hi/lo (hh, hl, lh) x 4 col-tiles.
#define MFMA12(AHI, ALO, BH_, BL_)                                             \
    {                                                                          \
        bf16x8 ah_ = (AHI), al_ = (ALO);                                       \
        _Pragma("unroll")                                                      \
        for (int q_ = 0; q_ < 4; ++q_) {                                       \
            accv[q_] = __builtin_amdgcn_mfma_f32_16x16x32_bf16(ah_, BH_[q_], accv[q_], 0, 0, 0); \
            accv[q_] = __builtin_amdgcn_mfma_f32_16x16x32_bf16(ah_, BL_[q_], accv[q_], 0, 0, 0); \
            accv[q_] = __builtin_amdgcn_mfma_f32_16x16x32_bf16(al_, BH_[q_], accv[q_], 0, 0, 0); \
        }                                                                      \
    }

// Pair of chunks: issue 4 coherent A-loads + 16 cached B-loads, one wait.
#define PAIR()                                                 \
    {                                                          \
        uint4 rah, ral, rbh, rbl;                              \
        sc_ld16(pah, rah); sc_ld16(pal, ral);                  \
        sc_ld16(pah + 16384, rbh); sc_ld16(pal + 16384, rbl);  \
        pah += 32768; pal += 32768;                            \
        LOADB(bha, bla);                                       \
        LOADB(bhb, blb);                                       \
        WAITV;                                                 \
        MFMA12(u2b(rah), u2b(ral), bha, bla);                  \
        MFMA12(u2b(rbh), u2b(rbl), bhb, blb);                  \
    }
#define TAIL1()                                                \
    {                                                          \
        uint4 rah, ral;                                        \
        sc_ld16(pah, rah); sc_ld16(pal, ral);                  \
        pah += 16384; pal += 16384;                            \
        LOADB(bht, blt);                                       \
        WAITV;                                                 \
        MFMA12(u2b(rah), u2b(ral), bht, blt);                  \
    }

// ---------------------------------------------------------------------------
// Weight pack: B-fragment layout (validated R3), hi/lo split.
// idx(k,n; KCt) = (((n>>4)*KCt + (k>>5))*4 + ((k>>3)&3))*128 + (n&15)*8 + (k&7)
// ---------------------------------------------------------------------------
__global__ __launch_bounds__(256) void pack_weights(
    const float* __restrict__ k0, const float* __restrict__ r0,
    const float* __restrict__ k1, const float* __restrict__ r1,
    const float* __restrict__ W,
    ushort* __restrict__ Bh0, ushort* __restrict__ Bl0,
    ushort* __restrict__ Bh1, ushort* __restrict__ Bl1,
    ushort* __restrict__ Wph, ushort* __restrict__ Wpl) {
    const int n0 = 576 * 2048;
    const int n1 = 1024 * 2048;
    const int nw = 512 * 64;
    const int total = n0 + n1 + nw;
    for (int idx = blockIdx.x * blockDim.x + threadIdx.x; idx < total;
         idx += gridDim.x * blockDim.x) {
        float v;
        ushort *dh, *dl;
        size_t didx;
        if (idx < n0) {
            int k = idx >> 11, n = idx & 2047;
            v = (k < D) ? k0[k * 2048 + n] : r0[(k - D) * 2048 + n];
            didx = (((size_t)(n >> 4) * KC0 + (k >> 5)) * 4 + ((k >> 3) & 3)) * 128
                   + (n & 15) * 8 + (k & 7);
            dh = Bh0; dl = Bl0;
        } else if (idx < n0 + n1) {
            int j = idx - n0;
            int k = j >> 11, n = j & 2047;
            v = (k < H) ? k1[k * 2048 + n] : r1[(k - H) * 2048 + n];
            didx = (((size_t)(n >> 4) * KC1 + (k >> 5)) * 4 + ((k >> 3) & 3)) * 128
                   + (n & 15) * 8 + (k & 7);
            dh = Bh1; dl = Bl1;
        } else {
            int j = idx - n0 - n1;
            int k = j >> 6, c = j & 63;
            v = W[k * 64 + c];
            didx = (((size_t)(c >> 4) * 16 + (k >> 5)) * 4 + ((k >> 3) & 3)) * 128
                   + (c & 15) * 8 + (k & 7);
            dh = Wph; dl = Wpl;
        }
        ushort hb_ = f2bf(v);
        dh[didx] = hb_;
        dl[didx] = f2bf(v - bf2f(hb_));
    }
}

__global__ __launch_bounds__(256) void init_zero(float4* __restrict__ z, int n4) {
    for (int i = blockIdx.x * blockDim.x + threadIdx.x; i < n4;
         i += gridDim.x * blockDim.x)
        z[i] = make_float4(0.f, 0.f, 0.f, 0.f);
}

// ---------------------------------------------------------------------------
// Fence-free grid barrier: relaxed agent atomics (no L2 invalidation).
// Visibility of h-data comes from sc0sc1 accesses + vmcnt(0) before arrival.
// ---------------------------------------------------------------------------
__device__ __forceinline__ void gbar(int* cnt, int* sense, int ep) {
    asm volatile("s_waitcnt vmcnt(0)" ::: "memory");
    __syncthreads();
    if (threadIdx.x == 0) {
        int old = __hip_atomic_fetch_add(cnt, 1, __ATOMIC_RELAXED,
                                         __HIP_MEMORY_SCOPE_AGENT);
        if (old == NBLK - 1) {
            __hip_atomic_store(cnt, 0, __ATOMIC_RELAXED, __HIP_MEMORY_SCOPE_AGENT);
            __hip_atomic_store(sense, ep, __ATOMIC_RELAXED, __HIP_MEMORY_SCOPE_AGENT);
        } else {
            while (__hip_atomic_load(sense, __ATOMIC_RELAXED,
                                     __HIP_MEMORY_SCOPE_AGENT) < ep)
                __builtin_amdgcn_s_sleep(4);
        }
    }
    __syncthreads();
    __builtin_amdgcn_sched_barrier(0);
}

// ---------------------------------------------------------------------------
// Persistent kernel: entire T-loop. 256 blocks (8 rowblocks x 32 hblocks,
// XCD-grouped by hblock -> each XCD's weight slice ~1.7MB stays L2-resident)
// x 512 threads (4 wrow x 2 K-half waves). c0/c1 in registers.
// ---------------------------------------------------------------------------
__global__ __launch_bounds__(512) void lstm_persistent(
    const float* __restrict__ inputs, const float* __restrict__ bvec,
    const float* __restrict__ b0, const float* __restrict__ b1,
    const ushort* __restrict__ Wr0h, const ushort* __restrict__ Wr0l,
    const ushort* __restrict__ Wr1h, const ushort* __restrict__ Wr1l,
    const ushort* __restrict__ Wph, const ushort* __restrict__ Wpl,
    ushort* __restrict__ h0Ah, ushort* __restrict__ h0Al,
    ushort* __restrict__ h1Ah, ushort* __restrict__ h1Al,
    ushort* __restrict__ h0Bh, ushort* __restrict__ h0Bl,
    ushort* __restrict__ h1Bh, ushort* __restrict__ h1Bl,
    float* __restrict__ h1f32, float* __restrict__ predout,
    int* __restrict__ cnt, int* __restrict__ sense) {
    __shared__ float red[4][4][64][4];       // 16 KB K-split reduce
    __shared__ ushort curAh[8][66][8];       // cur A-frags hi (row-padded)
    __shared__ ushort curAl[8][66][8];       // cur A-frags lo

    const int bid = blockIdx.x;
    const int xcd = bid & 7;
    const int wi = bid >> 3;
    const int rb = wi >> 2;                  // 0..7  rowblock (64 rows)
    const int hb = xcd * 4 + (wi & 3);       // 0..31 hblock (16 h-units)
    const int tid = threadIdx.x;
    const int wid = tid >> 6;
    const int l = tid & 63;
    const int wrow = wid & 3;                // row-subtile (16 rows)
    const int ks = wid >> 2;                 // K-half
    const int c16 = l & 15;
    const int sub = l >> 4;
    const int lr16 = wrow * 16 + c16;        // A-frag local row
    const int arow = rb * 64 + lr16;         // A-frag global row
    const int hc = hb * 16 + c16;            // h-unit owned in epilogue

    float c0r[4] = {0.f, 0.f, 0.f, 0.f};
    float c1r[4] = {0.f, 0.f, 0.f, 0.f};
    const float bI0 = b0[hc], bF0 = b0[H + hc], bG0 = b0[2 * H + hc], bO0 = b0[3 * H + hc];
    const float bI1 = b1[hc], bF1 = b1[H + hc], bG1 = b1[2 * H + hc], bO1 = b1[3 * H + hc];
    float bvr[4];
#pragma unroll
    for (int ct = 0; ct < 4; ++ct) bvr[ct] = bvec[ct * 16 + c16];

    const ushort* h0rh = h0Ah; const ushort* h0rl = h0Al;
    const ushort* h1rh = h1Ah; const ushort* h1rl = h1Al;
    ushort* h0wh = h0Bh; ushort* h0wl = h0Bl;
    ushort* h1wh = h1Bh; ushort* h1wl = h1Bl;

    const size_t fragoff = (size_t)sub * 128 + c16 * 8;
    const size_t arow8 = (size_t)arow * 8;

    for (int t = 0; t < T; ++t) {
        // =================== phase A ===================
        if (t > 0) {
            // ---- pred = h1(t-1) @ W + bvec (64 rows x 64 cols, K=512) ----
            f32x4 accv[4];
            accv[0] = accv[1] = accv[2] = accv[3] = (f32x4){0.f, 0.f, 0.f, 0.f};
            const int kcS = ks * 8;
            const ushort* ph[4]; const ushort* pl[4];
#pragma unroll
            for (int q = 0; q < 4; ++q) {
                size_t o = (size_t)(q * 16 + kcS) * 512 + fragoff;
                ph[q] = Wph + o; pl[q] = Wpl + o;
            }
            const ushort* pah = h1rh + ((size_t)kcS * 4 + sub) * 4096 + arow8;
            const ushort* pal = h1rl + ((size_t)kcS * 4 + sub) * 4096 + arow8;
            PAIR(); PAIR(); PAIR(); PAIR();   // 8 chunks
            if (ks == 1) {
#pragma unroll
                for (int q = 0; q < 4; ++q) *(f32x4*)&red[wrow][q][l][0] = accv[q];
            }
            __syncthreads();
            if (ks == 0) {
#pragma unroll
                for (int CT = 0; CT < 4; ++CT) {
                    f32x4 a = accv[CT];
                    a += *(f32x4*)&red[wrow][CT][l][0];
                    const int col = CT * 16 + c16;
#pragma unroll
                    for (int reg = 0; reg < 4; ++reg) {
                        int lr = wrow * 16 + sub * 4 + reg;
                        int grow = rb * 64 + lr;
                        float pv = a[reg] + bvr[CT];
                        if (hb == 0)
                            predout[(size_t)grow * PRED_ROW + (size_t)(t - 1) * D + col] = pv;
                        float xv = inputs[(size_t)grow * 8192 + (size_t)t * D + col];
                        float cv = (xv == MISSING_V) ? pv : xv;
                        ushort hbv = f2bf(cv);
                        curAh[col >> 3][lr][col & 7] = hbv;
                        curAl[col >> 3][lr][col & 7] = f2bf(cv - bf2f(hbv));
                    }
                }
            }
        } else {
            if (ks == 0) {
#pragma unroll
                for (int ct = 0; ct < 4; ++ct) {
                    const int col = ct * 16 + c16;
#pragma unroll
                    for (int reg = 0; reg < 4; ++reg) {
                        int lr = wrow * 16 + sub * 4 + reg;
                        int grow = rb * 64 + lr;
                        float cv = inputs[(size_t)grow * 8192 + col];
                        ushort hbv = f2bf(cv);
                        curAh[col >> 3][lr][col & 7] = hbv;
                        curAl[col >> 3][lr][col & 7] = f2bf(cv - bf2f(hbv));
                    }
                }
            }
        }
        __syncthreads();   // curA ready (and red free)

        // ---- L0 GEMM: z0 = [cur | h0(t-1)] @ Wr0, fused cell -> h0(t) ----
        {
            f32x4 accv[4];
            accv[0] = accv[1] = accv[2] = accv[3] = (f32x4){0.f, 0.f, 0.f, 0.f};
            const int kcS = ks * 9;
            const ushort* ph[4]; const ushort* pl[4];
#pragma unroll
            for (int q = 0; q < 4; ++q) {
                size_t o = ((size_t)(q * 32 + hb) * KC0 + kcS) * 512 + fragoff;
                ph[q] = Wr0h + o; pl[q] = Wr0l + o;
            }
            if (ks == 0) {
#pragma unroll
                for (int kc = 0; kc < 2; ++kc) {
                    LOADB(bhc, blc);
                    bf16x8 ahi = *(const bf16x8*)&curAh[kc * 4 + sub][lr16][0];
                    bf16x8 alo = *(const bf16x8*)&curAl[kc * 4 + sub][lr16][0];
                    MFMA12(ahi, alo, bhc, blc);
                }
                const ushort* pah = h0rh + (size_t)sub * 4096 + arow8;
                const ushort* pal = h0rl + (size_t)sub * 4096 + arow8;
                PAIR(); PAIR(); PAIR();       // 6 chunks
                TAIL1();                      // 7th
            } else {
                const ushort* pah = h0rh + ((size_t)7 * 4 + sub) * 4096 + arow8;
                const ushort* pal = h0rl + ((size_t)7 * 4 + sub) * 4096 + arow8;
                PAIR(); PAIR(); PAIR(); PAIR();   // 8 chunks
                TAIL1();                          // 9th
            }
            if (ks == 1) {
#pragma unroll
                for (int q = 0; q < 4; ++q) *(f32x4*)&red[wrow][q][l][0] = accv[q];
            }
            __syncthreads();
            if (ks == 0) {
#pragma unroll
                for (int q = 0; q < 4; ++q) accv[q] += *(f32x4*)&red[wrow][q][l][0];
#pragma unroll
                for (int reg = 0; reg < 4; ++reg) {
                    int grow = rb * 64 + wrow * 16 + sub * 4 + reg;
                    float zi = accv[0][reg] + bI0, zf = accv[1][reg] + bF0;
                    float zg = accv[2][reg] + bG0, zo = accv[3][reg] + bO0;
                    float cn = sigm(zf) * c0r[reg] + sigm(zi) * tanhf(zg);
                    c0r[reg] = cn;
                    float hn = sigm(zo) * tanhf(cn);
                    size_t po = ((size_t)(hc >> 3) * 512 + grow) * 8 + (hc & 7);
                    ushort hh = f2bf(hn);
                    sc_st16b(h0wh + po, hh);
                    sc_st16b(h0wl + po, f2bf(hn - bf2f(hh)));
                }
            }
        }
        gbar(cnt, sense, 2 * t + 1);

        // =================== phase B: L1 ===================
        {
            f32x4 accv[4];
            accv[0] = accv[1] = accv[2] = accv[3] = (f32x4){0.f, 0.f, 0.f, 0.f};
            const int kcS = ks * 16;
            const ushort* ph[4]; const ushort* pl[4];
#pragma unroll
            for (int q = 0; q < 4; ++q) {
                size_t o = ((size_t)(q * 32 + hb) * KC1 + kcS) * 512 + fragoff;
                ph[q] = Wr1h + o; pl[q] = Wr1l + o;
            }
            const ushort* pah = (ks == 0 ? (const ushort*)h0wh : h1rh) + (size_t)sub * 4096 + arow8;
            const ushort* pal = (ks == 0 ? (const ushort*)h0wl : h1rl) + (size_t)sub * 4096 + arow8;
            PAIR(); PAIR(); PAIR(); PAIR();
            PAIR(); PAIR(); PAIR(); PAIR();   // 16 chunks
            if (ks == 1) {
#pragma unroll
                for (int q = 0; q < 4; ++q) *(f32x4*)&red[wrow][q][l][0] = accv[q];
            }
            __syncthreads();
            if (ks == 0) {
#pragma unroll
                for (int q = 0; q < 4; ++q) accv[q] += *(f32x4*)&red[wrow][q][l][0];
#pragma unroll
                for (int reg = 0; reg < 4; ++reg) {
                    int grow = rb * 64 + wrow * 16 + sub * 4 + reg;
                    float zi = accv[0][reg] + bI1, zf = accv[1][reg] + bF1;
                    float zg = accv[2][reg] + bG1, zo = accv[3][reg] + bO1;
                    float cn = sigm(zf) * c1r[reg] + sigm(zi) * tanhf(zg);
                    c1r[reg] = cn;
                    float hn = sigm(zo) * tanhf(cn);
                    size_t po = ((size_t)(hc >> 3) * 512 + grow) * 8 + (hc & 7);
                    ushort hh = f2bf(hn);
                    sc_st16b(h1wh + po, hh);
                    sc_st16b(h1wl + po, f2bf(hn - bf2f(hh)));
                    if (t == T - 1) h1f32[(size_t)grow * H + hc] = hn;
                }
            }
        }
        gbar(cnt, sense, 2 * t + 2);

        { const ushort* s;
          s = h0rh; h0rh = h0wh; h0wh = (ushort*)s;
          s = h0rl; h0rl = h0wl; h0wl = (ushort*)s;
          s = h1rh; h1rh = h1wh; h1wh = (ushort*)s;
          s = h1rl; h1rl = h1wl; h1wl = (ushort*)s; }
    }
}

// ---------------------------------------------------------------------------
// Fused: M output copy + masked-squared-error reduction into *accum.
// ---------------------------------------------------------------------------
__global__ __launch_bounds__(256) void pred_loss_reduce(
    const float* __restrict__ pred, const float* __restrict__ targ,
    const float* __restrict__ mask, float* __restrict__ Mout,
    float* __restrict__ accum) {
    const int n4 = PRED_ELEMS / 4;
    float part = 0.f;
    for (int i = blockIdx.x * blockDim.x + threadIdx.x; i < n4;
         i += gridDim.x * blockDim.x) {
        float4 p = ((const float4*)pred)[i];
        float4 t = ((const float4*)targ)[i];
        float4 m = ((const float4*)mask)[i];
        ((float4*)Mout)[i] = m;
        float dx = (t.x - p.x) * m.x;
        float dy = (t.y - p.y) * m.y;
        float dz = (t.z - p.z) * m.z;
        float dw = (t.w - p.w) * m.w;
        part += dx * dx + dy * dy + dz * dz + dw * dw;
    }
#pragma unroll
    for (int off = 32; off > 0; off >>= 1) part += __shfl_down(part, off, 64);
    __shared__ float wsum[4];
    int lane = threadIdx.x & 63, wid = threadIdx.x >> 6;
    if (lane == 0) wsum[wid] = part;
    __syncthreads();
    if (threadIdx.x == 0)
        atomicAdd(accum, wsum[0] + wsum[1] + wsum[2] + wsum[3]);
}

// ---------------------------------------------------------------------------
// Final: logits = h1_last @ Wc + bc; log-softmax loss; accuracy.
// ---------------------------------------------------------------------------
__global__ __launch_bounds__(64) void final_loss(
    const float* __restrict__ h1, const float* __restrict__ Wc,
    const float* __restrict__ bc, const float* __restrict__ label,
    const float* __restrict__ lp_accum, float* __restrict__ loss,
    float* __restrict__ acc_out) {
    const int b = blockIdx.x;
    const int lane = threadIdx.x;
    float partial[NC];
#pragma unroll
    for (int c = 0; c < NC; ++c) partial[c] = 0.f;
    for (int k = lane; k < H; k += 64) {
        float hv = h1[(size_t)b * H + k];
#pragma unroll
        for (int c = 0; c < NC; ++c) partial[c] += hv * Wc[k * NC + c];
    }
    float logits[NC];
#pragma unroll
    for (int c = 0; c < NC; ++c) {
        float v = partial[c];
#pragma unroll
        for (int off = 32; off > 0; off >>= 1) v += __shfl_down(v, off, 64);
        logits[c] = v + bc[c];
    }
    if (lane == 0) {
        float mx = logits[0];
#pragma unroll
        for (int c = 1; c < NC; ++c) mx = fmaxf(mx, logits[c]);
        float se = 0.f;
#pragma unroll
        for (int c = 0; c < NC; ++c) se += expf(logits[c] - mx);
        float lse = logf(se);
        float lcls = 0.f;
        int am_p = 0, am_l = 0;
        float bp = logits[0], bl = label[(size_t)b * NC];
#pragma unroll
        for (int c = 0; c < NC; ++c) {
            float lt = label[(size_t)b * NC + c];
            lcls -= lt * (logits[c] - mx - lse);
            if (c > 0) {
                if (logits[c] > bp) { bp = logits[c]; am_p = c; }
                if (lt > bl) { bl = lt; am_l = c; }
            }
        }
        float lp = lp_accum[0] * (1.0f / (float)PRED_ELEMS) * (1.0f / (float)B);
        loss[b] = lcls + lp;
        acc_out[b] = (am_p == am_l) ? 1.f : 0.f;
    }
}

// ---------------------------------------------------------------------------
extern "C" void kernel_launch(void* const* d_in, const int* in_sizes, int n_in,
                              void* d_out, int out_size, void* d_ws,
                              size_t ws_size, hipStream_t stream) {
    const float* inputs  = (const float*)d_in[0];
    const float* ptarget = (const float*)d_in[1];
    const float* mask    = (const float*)d_in[2];
    const float* label   = (const float*)d_in[3];
    const float* W       = (const float*)d_in[4];
    const float* bvec    = (const float*)d_in[5];
    const float* k0      = (const float*)d_in[6];
    const float* r0      = (const float*)d_in[7];
    const float* b0      = (const float*)d_in[8];
    const float* k1      = (const float*)d_in[9];
    const float* r1      = (const float*)d_in[10];
    const float* b1      = (const float*)d_in[11];
    const float* Wc      = (const float*)d_in[12];
    const float* bc      = (const float*)d_in[13];

    float* out = (float*)d_out;
    float* loss    = out;
    float* predout = out + B;
    float* Mout    = out + B + PRED_ELEMS;
    float* accout  = out + B + 2 * (size_t)PRED_ELEMS;

    // ---- ws layout ----
    char* w = (char*)d_ws;
    ushort* h0Ah = (ushort*)w; w += (size_t)BH * 2;   // zeroed region start
    ushort* h0Al = (ushort*)w; w += (size_t)BH * 2;
    ushort* h1Ah = (ushort*)w; w += (size_t)BH * 2;
    ushort* h1Al = (ushort*)w; w += (size_t)BH * 2;
    int*    cnt   = (int*)w;
    int*    sense = (int*)(w + 4);
    float*  lp    = (float*)(w + 8);
    w += 64;
    const int zero_n4 = (int)((4 * (size_t)BH * 2 + 64) / 16);
    ushort* h0Bh = (ushort*)w; w += (size_t)BH * 2;
    ushort* h0Bl = (ushort*)w; w += (size_t)BH * 2;
    ushort* h1Bh = (ushort*)w; w += (size_t)BH * 2;
    ushort* h1Bl = (ushort*)w; w += (size_t)BH * 2;
    float*  h1f32 = (float*)w; w += (size_t)BH * 4;
    ushort* Wr0h = (ushort*)w; w += (size_t)576 * 2048 * 2;
    ushort* Wr0l = (ushort*)w; w += (size_t)576 * 2048 * 2;
    ushort* Wr1h = (ushort*)w; w += (size_t)1024 * 2048 * 2;
    ushort* Wr1l = (ushort*)w; w += (size_t)1024 * 2048 * 2;
    ushort* Wph  = (ushort*)w; w += (size_t)512 * 64 * 2;
    ushort* Wpl  = (ushort*)w; w += (size_t)512 * 64 * 2;

    pack_weights<<<2048, 256, 0, stream>>>(k0, r0, k1, r1, W,
                                           Wr0h, Wr0l, Wr1h, Wr1l, Wph, Wpl);
    init_zero<<<512, 256, 0, stream>>>((float4*)d_ws, zero_n4);

    lstm_persistent<<<NBLK, 512, 0, stream>>>(
        inputs, bvec, b0, b1, Wr0h, Wr0l, Wr1h, Wr1l, Wph, Wpl,
        h0Ah, h0Al, h1Ah, h1Al, h0Bh, h0Bl, h1Bh, h1Bl,
        h1f32, predout, cnt, sense);

    pred_loss_reduce<<<1024, 256, 0, stream>>>(predout, ptarget, mask, Mout, lp);
    final_loss<<<B, 64, 0, stream>>>(h1f32, Wc, bc, label, lp, loss, accout);
}